// Round 1
// baseline (10.369 us; speedup 1.0000x reference)
//
#include <hip/hip_runtime.h>

// Trigram backoff LM lookup, MI355X.
// Constants derived from the reference: V=8192, N=3, C2=32, C3=8.
#define TV   8192
#define TU   8193              // unigram nodes
#define TB2  262176            // U*C2 bigram nodes
#define TXP  270370            // X = U + B2 + 1
#define TG   2097407           // B3 - 1
#define TKU  2367776           // K + U - 1 (clip bound for ids indexing)
#define CHUNKS 8
#define VCHUNK (TV / CHUNKS)   // 1024 tokens per block

__global__ __launch_bounds__(256) void lookup_lm_kernel(
    const int* __restrict__ hist, const int* __restrict__ idxp,
    const int* __restrict__ pointers, const int* __restrict__ ids,
    const float* __restrict__ logs, float* __restrict__ out, int Bsz)
{
    __shared__ int   s_trig_id[8];
    __shared__ float s_trig_log[8];
    __shared__ int   s_big_id[32];
    __shared__ float s_big_log[32];
    __shared__ float s_base;   // bigram-ctx backoff (or 0 if no ctx)
    __shared__ float s_bo1;    // unigram h1 backoff
    __shared__ int   s_ctx;

    const int tid = threadIdx.x;
    const int b   = blockIdx.y;
    const int idx = idxp[0];                       // == N-1 == 2
    const int h0  = hist[(idx - 2) * Bsz + b];     // older token
    const int h1  = hist[(idx - 1) * Bsz + b];     // most recent token

    if (tid == 0) s_ctx = -1;
    __syncthreads();

    if (tid < 32) {
        // --- search bigram context node: child of unigram h0 with id == h1
        int off0 = pointers[h0];
        int nch0 = pointers[h0 + 1] - off0 + 1;
        int fc0  = h0 + off0;
        if (tid < nch0) {
            int node = fc0 + tid;
            int ci   = min(node, TKU) - TU;        // reference clips ids index
            if (ids[ci] == h1) s_ctx = node;       // unique match by construction
        }
        // --- stage bigram-level children of unigram h1 (for the (h1, v) stage)
        int offb = pointers[h1];
        int nchb = pointers[h1 + 1] - offb + 1;
        int fcb  = h1 + offb;
        int bid = -1; float blog = 0.f;
        if (tid < nchb) {
            int node = fcb + tid;
            int ci   = min(node, TKU) - TU;
            bid  = ids[ci];
            blog = logs[node];
        }
        s_big_id[tid]  = bid;
        s_big_log[tid] = blog;
        if (tid == 0) s_bo1 = logs[TXP + TG + h1];
    }
    __syncthreads();

    const int ctx = s_ctx;
    if (tid < 8) {
        // --- stage trigram children of ctx (8 children per bigram node)
        int tidv = -1; float tlog = 0.f;
        if (ctx >= 0) {
            int off1 = pointers[ctx];
            int nch1 = pointers[ctx + 1] - off1 + 1;
            int fc1  = ctx + off1;
            if (tid < nch1) {
                int node = fc1 + tid;
                int ci   = min(node, TKU) - TU;
                tidv = ids[ci];
                tlog = logs[node];
            }
            if (tid == 0) s_base = logs[TXP + TG + ctx];
        } else if (tid == 0) {
            s_base = 0.f;
        }
        s_trig_id[tid]  = tidv;
        s_trig_log[tid] = tlog;
    }
    __syncthreads();

    const float base = s_base;
    const float bo1  = s_bo1;
    const int vbase  = blockIdx.x * VCHUNK;
    float* orow = out + (size_t)b * TV;

    // 1024 tokens / block, 256 threads -> exactly one float4 group per thread
    for (int i = tid; i < VCHUNK / 4; i += 256) {
        int v0 = vbase + i * 4;
        float4 lg = *reinterpret_cast<const float4*>(logs + v0);
        float lgv[4] = {lg.x, lg.y, lg.z, lg.w};
        float r[4];
        #pragma unroll
        for (int j = 0; j < 4; ++j) {
            int v = v0 + j;
            float tlog = 0.f; bool tri = false;
            #pragma unroll
            for (int s = 0; s < 8; ++s) {
                if (s_trig_id[s] == v) { tlog = s_trig_log[s]; tri = true; }
            }
            float blog = 0.f; bool bi = false;
            #pragma unroll
            for (int s = 0; s < 32; ++s) {
                if (s_big_id[s] == v) { blog = s_big_log[s]; bi = true; }
            }
            float fallback = base + (bi ? blog : (bo1 + lgv[j]));
            r[j] = tri ? tlog : fallback;
        }
        float4 res = make_float4(r[0], r[1], r[2], r[3]);
        *reinterpret_cast<float4*>(orow + v0) = res;
    }
}

extern "C" void kernel_launch(void* const* d_in, const int* in_sizes, int n_in,
                              void* d_out, int out_size, void* d_ws, size_t ws_size,
                              hipStream_t stream) {
    const int*   hist     = (const int*)d_in[0];
    const int*   idxp     = (const int*)d_in[1];
    const int*   pointers = (const int*)d_in[2];
    const int*   ids      = (const int*)d_in[3];
    const float* logs     = (const float*)d_in[4];
    float* out = (float*)d_out;

    const int B = in_sizes[0] / 2;   // hist is (N-1, B) = (2, 128)
    dim3 grid(CHUNKS, B);
    lookup_lm_kernel<<<grid, 256, 0, stream>>>(hist, idxp, pointers, ids, logs, out, B);
}

// Round 2
// 10.078 us; speedup vs baseline: 1.0289x; 1.0289x over previous
//
#include <hip/hip_runtime.h>

// Trigram backoff LM lookup, MI355X.
// Constants derived from the reference: V=8192, N=3, C2=32, C3=8.
#define TV   8192
#define TU   8193              // unigram nodes
#define TXP  270370            // X = U + B2 + 1
#define TG   2097407           // B3 - 1
#define TKU  2367776           // K + U - 1 (clip bound for ids indexing)
#define CHUNKS 8
#define VCHUNK (TV / CHUNKS)   // 1024 tokens per block
#define SENT 0x7F800000u       // +inf bit pattern; logs are all finite

__global__ __launch_bounds__(256) void lookup_lm_kernel(
    const int* __restrict__ hist, const int* __restrict__ idxp,
    const int* __restrict__ pointers, const int* __restrict__ ids,
    const float* __restrict__ logs, float* __restrict__ out, int Bsz)
{
    __shared__ unsigned s_over[VCHUNK];   // per-token override values (bits)
    __shared__ int   s_ptr[33];           // speculative pointers[fc0 .. fc0+32]
    __shared__ float s_base;              // ctx backoff (0 if no ctx)
    __shared__ float s_bo1;               // unigram h1 backoff
    __shared__ int   s_ctx;

    const int tid   = threadIdx.x;
    const int b     = blockIdx.y;
    const int vbase = blockIdx.x * VCHUNK;

    // ---- R1: all independent loads issued up front -----------------------
    // fallback logs[v] prefetch (consumed only at the very end)
    float4 lg4 = *reinterpret_cast<const float4*>(logs + vbase + tid * 4);
    int h0  = hist[b];            // speculative: idx == 2 (always, per setup)
    int h1  = hist[Bsz + b];
    int idx = idxp[0];
    if (idx != 2) {               // defensive fallback, uniform branch
        h0 = hist[(idx - 2) * Bsz + b];
        h1 = hist[(idx - 1) * Bsz + b];
    }

    // init override table + ctx sentinel (no global dependency)
    *reinterpret_cast<uint4*>(&s_over[tid * 4]) = make_uint4(SENT, SENT, SENT, SENT);
    if (tid == 0) s_ctx = -1;

    // ---- R2: pointer rows for h0, h1 (uniform -> scalar loads) -----------
    const int p_h0  = pointers[h0];
    const int p_h0n = pointers[h0 + 1];
    const int p_h1  = pointers[h1];
    const int p_h1n = pointers[h1 + 1];

    const int fc0  = h0 + p_h0;           // first bigram child of h0
    const int nch0 = p_h0n - p_h0 + 1;
    const int fcb  = h1 + p_h1;           // first bigram child of h1
    const int nchb = p_h1n - p_h1 + 1;

    __syncthreads();  // s_over/s_ctx init visible before R3 writes

    // ---- R3: parallel staged loads (different waves, all independent) ----
    int big_id = -1; float big_log = 0.f;
    if (tid < 32) {
        // ctx search: child of h0 with id == h1 (unique by construction)
        if (tid < nch0) {
            int node = fc0 + tid;
            int cid  = ids[min(node, TKU) - TU];
            if (cid == h1) s_ctx = node;
        }
    } else if (tid < 64) {
        // bigram stage: children of h1 (kept in registers for the scatter)
        int s = tid - 32;
        if (s < nchb) {
            int node = fcb + s;
            big_id  = ids[min(node, TKU) - TU];
            big_log = logs[node];
        }
    } else if (tid < 97) {
        // speculative pointers for all 32 ctx candidates (+1 for counts)
        s_ptr[tid - 64] = pointers[fc0 + (tid - 64)];
    } else if (tid == 97) {
        s_bo1 = logs[TXP + TG + h1];
    }
    __syncthreads();

    // ---- R4: trigram stage (pointer already staged -> single load round) -
    const int ctx = s_ctx;
    int tri_id = -1; float tri_log = 0.f;
    if (ctx >= 0) {
        if (tid < 8) {
            int ci   = ctx - fc0;         // in [0, 32)
            int offc = s_ptr[ci];
            int nchc = s_ptr[ci + 1] - offc + 1;
            if (tid < nchc) {
                int node = ctx + offc + tid;
                tri_id  = ids[min(node, TKU) - TU];
                tri_log = logs[node];
            }
        } else if (tid == 8) {
            s_base = logs[TXP + TG + ctx];
        }
    } else if (tid == 8) {
        s_base = 0.f;
    }
    __syncthreads();

    const float base = s_base;

    // ---- scatter overrides: bigram first, trigram wins on conflict -------
    if (big_id >= vbase && big_id < vbase + VCHUNK) {
        s_over[big_id - vbase] = __float_as_uint(base + big_log);
    }
    __syncthreads();
    if (tri_id >= vbase && tri_id < vbase + VCHUNK) {
        s_over[tri_id - vbase] = __float_as_uint(tri_log);
    }
    __syncthreads();

    // ---- sweep: 1 ds_read_b128 + 4 selects + 1 global_store_dwordx4 ------
    const float fb = base + s_bo1;        // matches reference add order
    uint4 ov = *reinterpret_cast<const uint4*>(&s_over[tid * 4]);
    float4 res;
    res.x = (ov.x == SENT) ? fb + lg4.x : __uint_as_float(ov.x);
    res.y = (ov.y == SENT) ? fb + lg4.y : __uint_as_float(ov.y);
    res.z = (ov.z == SENT) ? fb + lg4.z : __uint_as_float(ov.z);
    res.w = (ov.w == SENT) ? fb + lg4.w : __uint_as_float(ov.w);
    *reinterpret_cast<float4*>(out + (size_t)b * TV + vbase + tid * 4) = res;
}

extern "C" void kernel_launch(void* const* d_in, const int* in_sizes, int n_in,
                              void* d_out, int out_size, void* d_ws, size_t ws_size,
                              hipStream_t stream) {
    const int*   hist     = (const int*)d_in[0];
    const int*   idxp     = (const int*)d_in[1];
    const int*   pointers = (const int*)d_in[2];
    const int*   ids      = (const int*)d_in[3];
    const float* logs     = (const float*)d_in[4];
    float* out = (float*)d_out;

    const int B = in_sizes[0] / 2;   // hist is (N-1, B) = (2, 128)
    dim3 grid(CHUNKS, B);
    lookup_lm_kernel<<<grid, 256, 0, stream>>>(hist, idxp, pointers, ids, logs, out, B);
}